// Round 1
// baseline (3366.064 us; speedup 1.0000x reference)
//
#include <hip/hip_runtime.h>
#include <math.h>

// ---------------------------------------------------------------------------
// ODERGRU pipeline for MI355X. Stages:
//  K1: einsum('bscft,fm->bscmt') -> h1 (3200, 96, 29)
//  K2: conv1d 96->96 k5 VALID + bias -> h2 (3200,96,25) + per-image BN partials
//  K3: reduce BN1 stats -> affine A1,B1 per channel (f64 accumulate)
//  K4: conv1d 96->16 k5 (applies BN1+lrelu on load) + bias -> h3 (3200,16,21) + BN2 partials
//  K5: reduce BN2 stats -> A2,B2
//  K6: per-image OAS-shrunk covariance + 16x16 Cholesky -> x_d (3200,16), x_o (3200,120)
//  K7: 64 independent per-batch-row scans (50 steps x 4 Euler x 4-layer MLP + 2 GRUs) + classifier
// ---------------------------------------------------------------------------

#define BB 64
#define SS 50
#define NIMG 3200           // B*S
#define CIN 96
#define TT 29
#define T1 25
#define T2 21
#define DD 16
#define MOFF 120
#define HID 136
#define ODE_U 256

__device__ __forceinline__ float sigm(float x) { return 1.f / (1.f + expf(-x)); }

// ------------------------------ K1: filterbank ------------------------------
__global__ __launch_bounds__(256) void k1_fb(const float* __restrict__ x,
                                             const float* __restrict__ fw,
                                             const float* __restrict__ st,
                                             float* __restrict__ h1) {
  __shared__ __align__(16) float ws[129 * 32];   // fw*s_tri, [f][m]
  __shared__ __align__(16) float xs[129 * 32];   // x chunk, [(c*43+f)][t] padded to 32
  const int tid = threadIdx.x;
  const int n = blockIdx.x;
  const float* xp = x + (size_t)n * 11223;       // 3*129*29

  for (int i = tid; i < 4128; i += 256) ws[i] = fw[i] * st[i];

  float acc[4][4];
#pragma unroll
  for (int i = 0; i < 4; ++i)
#pragma unroll
    for (int j = 0; j < 4; ++j) acc[i][j] = 0.f;

  const int c = tid / 64;
  const int rem = tid % 64;
  const int m0 = (rem / 8) * 4;
  const int t0 = (rem % 8) * 4;

  for (int fc = 0; fc < 3; ++fc) {
    __syncthreads();
    for (int i = tid; i < 3741; i += 256) {       // 3*43*29
      int cc = i / 1247;
      int r = i - cc * 1247;
      int f = r / 29;
      int t = r - f * 29;
      xs[(cc * 43 + f) * 32 + t] = xp[cc * 3741 + (fc * 43 + f) * 29 + t];
    }
    for (int i = tid; i < 129; i += 256) {
      xs[i * 32 + 29] = 0.f; xs[i * 32 + 30] = 0.f; xs[i * 32 + 31] = 0.f;
    }
    __syncthreads();
    if (tid < 192) {
      const float* xb = xs + (c * 43) * 32 + t0;
      const float* wb = ws + (fc * 43) * 32 + m0;
      for (int f = 0; f < 43; ++f) {
        float4 xv = *(const float4*)(xb + f * 32);
        float4 wv = *(const float4*)(wb + f * 32);
        float xa[4] = {xv.x, xv.y, xv.z, xv.w};
        float wa[4] = {wv.x, wv.y, wv.z, wv.w};
#pragma unroll
        for (int i = 0; i < 4; ++i)
#pragma unroll
          for (int j = 0; j < 4; ++j) acc[i][j] += wa[i] * xa[j];
      }
    }
  }
  if (tid < 192) {
    const int nt = (t0 == 28) ? 1 : 4;
    for (int i = 0; i < 4; ++i)
      for (int j = 0; j < nt; ++j)
        h1[(size_t)n * 2784 + (size_t)(c * 32 + m0 + i) * 29 + (t0 + j)] = acc[i][j];
  }
}

// ------------------------------ K2: conv1 ------------------------------
// 2 images/WG; thread (img, co) computes all 25 t outputs. 192 compute threads.
__global__ __launch_bounds__(256) void k2_conv1(const float* __restrict__ h1,
                                                const float* __restrict__ w,
                                                const float* __restrict__ bias,
                                                float* __restrict__ h2,
                                                float* __restrict__ part1) {
  __shared__ __align__(16) float ins[2 * 96 * 32];  // [img][ci][t pad 32]
  __shared__ __align__(16) float wls[96 * 81];      // [co][ci16*5 pad 81]
  const int tid = threadIdx.x;
  const int wg = blockIdx.x;

  for (int i = tid; i < 2 * 2784; i += 256) {
    int img = i / 2784;
    int e = i - img * 2784;
    int ci = e / 29;
    int t = e - ci * 29;
    ins[img * 3072 + ci * 32 + t] = h1[(size_t)(wg * 2 + img) * 2784 + e];
  }

  const int img = tid / 96;
  const int co = tid - img * 96;
  float acc[25];
#pragma unroll
  for (int t = 0; t < 25; ++t) acc[t] = 0.f;

  for (int cc = 0; cc < 6; ++cc) {
    __syncthreads();
    for (int i = tid; i < 7680; i += 256) {
      int cw = i / 80;
      int r = i - cw * 80;
      wls[cw * 81 + r] = w[cw * 480 + cc * 80 + r];
    }
    __syncthreads();
    if (tid < 192) {
      for (int ci = 0; ci < 16; ++ci) {
        float xv[29];
#pragma unroll
        for (int j = 0; j < 29; ++j) xv[j] = ins[img * 3072 + (cc * 16 + ci) * 32 + j];
        float wv[5];
#pragma unroll
        for (int d = 0; d < 5; ++d) wv[d] = wls[co * 81 + ci * 5 + d];
#pragma unroll
        for (int t = 0; t < 25; ++t) {
          float s = acc[t];
#pragma unroll
          for (int d = 0; d < 5; ++d) s += xv[t + d] * wv[d];
          acc[t] = s;
        }
      }
    }
  }
  if (tid < 192) {
    const int n = wg * 2 + img;
    const float bval = bias[co];
    float s1 = 0.f, s2 = 0.f;
    for (int t = 0; t < 25; ++t) {
      float v = acc[t] + bval;
      h2[(size_t)n * 2400 + co * 25 + t] = v;
      s1 += v;
      s2 += v * v;
    }
    part1[((size_t)n * 96 + co) * 2 + 0] = s1;
    part1[((size_t)n * 96 + co) * 2 + 1] = s2;
  }
}

// ------------------------------ K3/K5: BN reduce ------------------------------
__global__ void k3_bn1(const float* __restrict__ part, const float* __restrict__ g,
                       const float* __restrict__ be, float* __restrict__ ab) {
  int c = threadIdx.x;
  if (c >= 96) return;
  double s = 0.0, q = 0.0;
  for (int n = 0; n < NIMG; ++n) {
    s += (double)part[((size_t)n * 96 + c) * 2 + 0];
    q += (double)part[((size_t)n * 96 + c) * 2 + 1];
  }
  double mu = s / 80000.0;
  double var = q / 80000.0 - mu * mu;
  float A = (float)((double)g[c] / sqrt(var + 1e-5));
  float Bv = (float)((double)be[c] - mu * (double)A);
  ab[c * 2 + 0] = A;
  ab[c * 2 + 1] = Bv;
}

__global__ void k5_bn2(const float* __restrict__ part, const float* __restrict__ g,
                       const float* __restrict__ be, float* __restrict__ ab) {
  int c = threadIdx.x;
  if (c >= 16) return;
  double s = 0.0, q = 0.0;
  for (int w = 0; w < 800; ++w) {
    s += (double)part[((size_t)w * 16 + c) * 2 + 0];
    q += (double)part[((size_t)w * 16 + c) * 2 + 1];
  }
  double mu = s / 67200.0;
  double var = q / 67200.0 - mu * mu;
  float A = (float)((double)g[c] / sqrt(var + 1e-5));
  float Bv = (float)((double)be[c] - mu * (double)A);
  ab[c * 2 + 0] = A;
  ab[c * 2 + 1] = Bv;
}

// ------------------------------ K4: conv2 ------------------------------
// 4 images/WG; thread = (img4, co16, tg4). Applies BN1 affine + lrelu on load.
__global__ __launch_bounds__(256) void k4_conv2(const float* __restrict__ h2,
                                                const float* __restrict__ w,
                                                const float* __restrict__ bias,
                                                const float* __restrict__ bn1,
                                                float* __restrict__ h3,
                                                float* __restrict__ part2) {
  __shared__ __align__(16) float ins[4 * 96 * 26];  // [img][ci][t pad 26]
  __shared__ __align__(16) float wls[16 * 241];     // [co][ci48*5 pad 241]
  __shared__ float A1s[96], B1s[96];
  __shared__ float red[16 * 16 * 2];
  const int tid = threadIdx.x;
  const int wg = blockIdx.x;

  if (tid < 96) {
    A1s[tid] = bn1[tid * 2 + 0];
    B1s[tid] = bn1[tid * 2 + 1];
  }
  __syncthreads();
  for (int i = tid; i < 9600; i += 256) {
    int img = i / 2400;
    int e = i - img * 2400;
    int ci = e / 25;
    int t = e - ci * 25;
    float v = h2[(size_t)(wg * 4 + img) * 2400 + e];
    v = A1s[ci] * v + B1s[ci];
    v = (v >= 0.f) ? v : 0.01f * v;
    ins[img * 2496 + ci * 26 + t] = v;
  }
  for (int i = tid; i < 4 * 96; i += 256) ins[(i / 96) * 2496 + (i % 96) * 26 + 25] = 0.f;

  const int img = tid >> 6;
  const int co = (tid >> 2) & 15;
  const int tg = tid & 3;
  const int t0s[4] = {0, 6, 11, 16};
  const int t0 = t0s[tg];
  const int tl = (tg == 0) ? 6 : 5;
  float acc[6] = {0.f, 0.f, 0.f, 0.f, 0.f, 0.f};

  for (int cc = 0; cc < 2; ++cc) {
    __syncthreads();
    for (int i = tid; i < 3840; i += 256) {
      int cw = i / 240;
      int r = i - cw * 240;
      wls[cw * 241 + r] = w[cw * 480 + cc * 240 + r];
    }
    __syncthreads();
    for (int ci = 0; ci < 48; ++ci) {
      float xv[10];
#pragma unroll
      for (int j = 0; j < 10; ++j) xv[j] = ins[img * 2496 + (cc * 48 + ci) * 26 + t0 + j];
      float wv[5];
#pragma unroll
      for (int d = 0; d < 5; ++d) wv[d] = wls[co * 241 + ci * 5 + d];
#pragma unroll
      for (int t = 0; t < 6; ++t) {
        float s = acc[t];
#pragma unroll
        for (int d = 0; d < 5; ++d) s += xv[t + d] * wv[d];
        acc[t] = s;
      }
    }
  }
  const float bval = bias[co];
  float s1 = 0.f, s2 = 0.f;
  const int n = wg * 4 + img;
  for (int t = 0; t < 6; ++t) {
    if (t < tl) {
      float v = acc[t] + bval;
      h3[(size_t)n * 336 + co * 21 + t0 + t] = v;
      s1 += v;
      s2 += v * v;
    }
  }
  red[(co * 16 + img * 4 + tg) * 2 + 0] = s1;
  red[(co * 16 + img * 4 + tg) * 2 + 1] = s2;
  __syncthreads();
  if (tid < 16) {
    float s = 0.f, q = 0.f;
    for (int k = 0; k < 16; ++k) {
      s += red[(tid * 16 + k) * 2 + 0];
      q += red[(tid * 16 + k) * 2 + 1];
    }
    part2[((size_t)wg * 16 + tid) * 2 + 0] = s;
    part2[((size_t)wg * 16 + tid) * 2 + 1] = q;
  }
}

// ------------------------------ K6: OAS + Cholesky ------------------------------
// One wave per image (4 images/WG). Applies BN2 affine + lrelu on load.
__global__ __launch_bounds__(256) void k6_oas(const float* __restrict__ h3,
                                              const float* __restrict__ bn2,
                                              float* __restrict__ xd,
                                              float* __restrict__ xo) {
  __shared__ float X[4][21 * 17 + 3];
  __shared__ float A[4][16 * 17];
  __shared__ float mcol[4][16];
  const int tid = threadIdx.x;
  const int wid = tid >> 6;
  const int lane = tid & 63;
  const int n = blockIdx.x * 4 + wid;
  const float* hp = h3 + (size_t)n * 336;

  for (int e = lane; e < 336; e += 64) {
    int c = e / 21;
    int t = e - c * 21;
    float v = hp[e];
    v = bn2[c * 2 + 0] * v + bn2[c * 2 + 1];
    v = (v >= 0.f) ? v : 0.01f * v;
    X[wid][t * 17 + c] = v;
  }
  __syncthreads();
  if (lane < 16) {
    float s = 0.f;
    for (int t = 0; t < 21; ++t) s += X[wid][t * 17 + lane];
    mcol[wid][lane] = s * (1.f / 21.f);
  }
  __syncthreads();
  for (int e = lane; e < 336; e += 64) {
    int t = e / 16;
    int c = e - t * 16;
    X[wid][t * 17 + c] -= mcol[wid][c];
  }
  __syncthreads();

  float tr_p = 0.f, al_p = 0.f;
  float ent[3];
  int ei[3], ej[3], ne = 0;
  for (int e = lane; e < 136; e += 64) {
    int i = 0, e2 = e;
    while (e2 >= 16 - i) { e2 -= 16 - i; i++; }
    int j = i + e2;
    float s = 0.f;
    for (int t = 0; t < 21; ++t) s += X[wid][t * 17 + i] * X[wid][t * 17 + j];
    s *= (1.f / 20.f);
    ent[ne] = s; ei[ne] = i; ej[ne] = j; ne++;
    if (i == j) tr_p += s;
    al_p += s * s * ((i == j) ? 1.f : 2.f);
  }
  for (int m = 1; m < 64; m <<= 1) {
    tr_p += __shfl_xor(tr_p, m);
    al_p += __shfl_xor(al_p, m);
  }
  const float mu = tr_p * (1.f / 16.f);
  const float alpha = al_p * (1.f / 256.f);
  const float num = alpha + mu * mu;
  const float den = 22.f * (alpha - mu * mu * (1.f / 16.f));
  const float shr = (den == 0.f) ? 1.f : fminf(num / den, 1.f);
  for (int q = 0; q < ne; ++q) {
    float c = (1.f - shr) * ent[q] + ((ei[q] == ej[q]) ? shr * mu : 0.f);
    A[wid][ei[q] * 17 + ej[q]] = c;
    A[wid][ej[q] * 17 + ei[q]] = c;
  }
  __syncthreads();

  for (int k = 0; k < 16; ++k) {
    float akk = A[wid][k * 17 + k];
    __syncthreads();
    float d = sqrtf(akk);
    float rd = 1.f / d;
    if (lane == k) A[wid][k * 17 + k] = d;
    if (lane > k && lane < 16) A[wid][lane * 17 + k] *= rd;
    __syncthreads();
    if (lane > k && lane < 16) {
      float Lik = A[wid][lane * 17 + k];
      for (int j = k + 1; j <= lane; ++j) A[wid][lane * 17 + j] -= Lik * A[wid][j * 17 + k];
    }
    __syncthreads();
  }
  if (lane < 16) xd[(size_t)n * 16 + lane] = A[wid][lane * 17 + lane];
  for (int p = lane; p < 120; p += 64) {
    int i = 1, p2 = p;
    while (p2 >= i) { p2 -= i; i++; }
    xo[(size_t)n * 120 + p] = A[wid][i * 17 + p2];
  }
}

// ------------------------------ K7: scan ------------------------------
__global__ __launch_bounds__(256) void k7_scan(
    const float* __restrict__ xdv, const float* __restrict__ xov,
    const float* __restrict__ wxd, const float* __restrict__ whd, const float* __restrict__ bdv,
    const float* __restrict__ wxo, const float* __restrict__ who, const float* __restrict__ bov,
    const float* __restrict__ w0, const float* __restrict__ b0,
    const float* __restrict__ w1, const float* __restrict__ b1,
    const float* __restrict__ w2, const float* __restrict__ b2,
    const float* __restrict__ w3, const float* __restrict__ b3,
    const float* __restrict__ cw, const float* __restrict__ cbv,
    float* __restrict__ out) {
  __shared__ __align__(16) float hc[136];
  __shared__ __align__(16) float bufA[256];
  __shared__ __align__(16) float bufB[256];
  __shared__ __align__(16) float xdl[16];
  __shared__ __align__(16) float xol[120];
  __shared__ __align__(16) float g[720];
  __shared__ __align__(16) float g2[96];
  const int tid = threadIdx.x;
  const int b = blockIdx.x;
  if (tid < 136) hc[tid] = 0.f;
  __syncthreads();

  for (int s = 0; s < 50; ++s) {
    if (tid < 16) xdl[tid] = xdv[(size_t)(b * 50 + s) * 16 + tid];
    if (tid >= 64 && tid < 184) xol[tid - 64] = xov[(size_t)(b * 50 + s) * 120 + (tid - 64)];

    for (int e = 0; e < 4; ++e) {
      // L1: hc(136) -> bufA(256), tanh
      {
        float a0 = b0[tid], a1 = 0.f;
        const float* wp = w0 + tid;
#pragma unroll 2
        for (int k = 0; k < 136; k += 8) {
          float4 v0 = *(const float4*)(hc + k);
          float4 v1 = *(const float4*)(hc + k + 4);
          a0 += v0.x * wp[0] + v0.y * wp[256] + v0.z * wp[512] + v0.w * wp[768];
          a1 += v1.x * wp[1024] + v1.y * wp[1280] + v1.z * wp[1536] + v1.w * wp[1792];
          wp += 2048;
        }
        bufA[tid] = tanhf(a0 + a1);
      }
      __syncthreads();
      // L2: bufA -> bufB
      {
        float a0 = b1[tid], a1 = 0.f;
        const float* wp = w1 + tid;
#pragma unroll 2
        for (int k = 0; k < 256; k += 8) {
          float4 v0 = *(const float4*)(bufA + k);
          float4 v1 = *(const float4*)(bufA + k + 4);
          a0 += v0.x * wp[0] + v0.y * wp[256] + v0.z * wp[512] + v0.w * wp[768];
          a1 += v1.x * wp[1024] + v1.y * wp[1280] + v1.z * wp[1536] + v1.w * wp[1792];
          wp += 2048;
        }
        bufB[tid] = tanhf(a0 + a1);
      }
      __syncthreads();
      // L3: bufB -> bufA
      {
        float a0 = b2[tid], a1 = 0.f;
        const float* wp = w2 + tid;
#pragma unroll 2
        for (int k = 0; k < 256; k += 8) {
          float4 v0 = *(const float4*)(bufB + k);
          float4 v1 = *(const float4*)(bufB + k + 4);
          a0 += v0.x * wp[0] + v0.y * wp[256] + v0.z * wp[512] + v0.w * wp[768];
          a1 += v1.x * wp[1024] + v1.y * wp[1280] + v1.z * wp[1536] + v1.w * wp[1792];
          wp += 2048;
        }
        bufA[tid] = tanhf(a0 + a1);
      }
      __syncthreads();
      // L4: bufA -> hc (+= DT * out)
      if (tid < 136) {
        float a0 = b3[tid], a1 = 0.f;
        const float* wp = w3 + tid;
#pragma unroll 2
        for (int k = 0; k < 256; k += 8) {
          float4 v0 = *(const float4*)(bufA + k);
          float4 v1 = *(const float4*)(bufA + k + 4);
          a0 += v0.x * wp[0] + v0.y * wp[136] + v0.z * wp[272] + v0.w * wp[408];
          a1 += v1.x * wp[544] + v1.y * wp[680] + v1.z * wp[816] + v1.w * wp[952];
          wp += 1088;
        }
        hc[tid] += 0.25f * (a0 + a1);
      }
      __syncthreads();
    }

    // Gate dot products: 720 o-dots (K=120) + 96 d-dots (K=16)
    for (int idx = tid; idx < 816; idx += 256) {
      if (idx < 720) {
        const int which = (idx >= 360) ? 1 : 0;
        const int col = which ? idx - 360 : idx;
        const float* W = which ? who : wxo;
        const float* src = which ? (hc + 16) : xol;
        float a0 = 0.f, a1 = 0.f;
        const float* wp = W + col;
#pragma unroll 2
        for (int k = 0; k < 120; k += 8) {
          float4 v0 = *(const float4*)(src + k);
          float4 v1 = *(const float4*)(src + k + 4);
          a0 += v0.x * wp[0] + v0.y * wp[360] + v0.z * wp[720] + v0.w * wp[1080];
          a1 += v1.x * wp[1440] + v1.y * wp[1800] + v1.z * wp[2160] + v1.w * wp[2520];
          wp += 2880;
        }
        g[idx] = a0 + a1;
      } else {
        const int j = idx - 720;
        const int which = (j >= 48) ? 1 : 0;
        const int col = which ? j - 48 : j;
        const float* W = which ? whd : wxd;
        float a = 0.f;
#pragma unroll
        for (int k = 0; k < 16; ++k) {
          float sv = which ? expf(hc[k]) : xdl[k];
          a += sv * fabsf(W[k * 48 + col]);
        }
        g2[j] = a;
      }
    }
    __syncthreads();

    if (tid < 120) {
      float r = sigm(g[tid] + g[360 + tid] + bov[tid]);
      float z = sigm(g[120 + tid] + g[480 + tid] + bov[120 + tid]);
      float ng = tanhf(g[240 + tid] + r * g[600 + tid] + bov[240 + tid]);
      float ho = hc[16 + tid];
      hc[16 + tid] = ng + z * (ho - ng);
    } else if (tid >= 128 && tid < 144) {
      int t = tid - 128;
      float ixr = g2[t], ixi = g2[16 + t], ixn = g2[32 + t];
      float hhr = g2[48 + t], hhi = g2[64 + t], hhn = g2[80 + t];
      float br = fabsf(bdv[t]), bi = fabsf(bdv[16 + t]), bn = fabsf(bdv[32 + t]);
      float r = sigm(br * ixr * hhr);
      float z = sigm(bi * ixi * hhi);
      float sp = bn * ixn * r * hhn;
      float ng = (sp > 20.f) ? sp : log1pf(expf(sp));
      float ldp = hc[t];
      hc[t] = z * ldp + (1.f - z) * logf(ng);
    }
    __syncthreads();
  }

  if (tid < 5) {
    float a = cbv[tid];
    for (int j = 0; j < 136; ++j) a += hc[j] * cw[j * 5 + tid];
    out[(size_t)b * 5 + tid] = a;
  }
}

// ------------------------------ launch ------------------------------
extern "C" void kernel_launch(void* const* d_in, const int* in_sizes, int n_in,
                              void* d_out, int out_size, void* d_ws, size_t ws_size,
                              hipStream_t stream) {
  const float* x       = (const float*)d_in[0];
  const float* fw      = (const float*)d_in[1];
  const float* s_tri   = (const float*)d_in[2];
  const float* conv1_w = (const float*)d_in[3];
  const float* conv1_b = (const float*)d_in[4];
  const float* bn1_g   = (const float*)d_in[5];
  const float* bn1_b   = (const float*)d_in[6];
  const float* conv2_w = (const float*)d_in[7];
  const float* conv2_b = (const float*)d_in[8];
  const float* bn2_g   = (const float*)d_in[9];
  const float* bn2_b   = (const float*)d_in[10];
  const float* wx_d    = (const float*)d_in[11];
  const float* wh_d    = (const float*)d_in[12];
  const float* bias_d  = (const float*)d_in[13];
  const float* wx_o    = (const float*)d_in[14];
  const float* wh_o    = (const float*)d_in[15];
  const float* bias_o  = (const float*)d_in[16];
  const float* ode_w0  = (const float*)d_in[17];
  const float* ode_b0  = (const float*)d_in[18];
  const float* ode_w1  = (const float*)d_in[19];
  const float* ode_b1  = (const float*)d_in[20];
  const float* ode_w2  = (const float*)d_in[21];
  const float* ode_b2  = (const float*)d_in[22];
  const float* ode_w3  = (const float*)d_in[23];
  const float* ode_b3  = (const float*)d_in[24];
  const float* cls_w   = (const float*)d_in[25];
  const float* cls_b   = (const float*)d_in[26];

  float* ws = (float*)d_ws;
  // region 0: h1 during K1/K2, then reused for h3/xd/xo
  float* h1  = ws;                    // 8,908,800 floats
  float* h3  = ws;                    // 1,075,200 floats (after h1 dead)
  float* xd  = ws + 1075200;          // 51,200
  float* xo  = ws + 1126400;          // 384,000
  float* h2  = ws + 8908800;          // 7,680,000
  float* p1  = ws + 16588800;         // 614,400
  float* bn1 = ws + 17203200;         // 192
  float* p2  = ws + 17203392;         // 25,600
  float* bn2 = ws + 17228992;         // 32

  hipLaunchKernelGGL(k1_fb,   dim3(NIMG),     dim3(256), 0, stream, x, fw, s_tri, h1);
  hipLaunchKernelGGL(k2_conv1,dim3(NIMG/2),   dim3(256), 0, stream, h1, conv1_w, conv1_b, h2, p1);
  hipLaunchKernelGGL(k3_bn1,  dim3(1),        dim3(128), 0, stream, p1, bn1_g, bn1_b, bn1);
  hipLaunchKernelGGL(k4_conv2,dim3(NIMG/4),   dim3(256), 0, stream, h2, conv2_w, conv2_b, bn1, h3, p2);
  hipLaunchKernelGGL(k5_bn2,  dim3(1),        dim3(64),  0, stream, p2, bn2_g, bn2_b, bn2);
  hipLaunchKernelGGL(k6_oas,  dim3(NIMG/4),   dim3(256), 0, stream, h3, bn2, xd, xo);
  hipLaunchKernelGGL(k7_scan, dim3(BB),       dim3(256), 0, stream,
                     xd, xo, wx_d, wh_d, bias_d, wx_o, wh_o, bias_o,
                     ode_w0, ode_b0, ode_w1, ode_b1, ode_w2, ode_b2, ode_w3, ode_b3,
                     cls_w, cls_b, (float*)d_out);
}